// Round 1
// baseline (1162.564 us; speedup 1.0000x reference)
//
#include <hip/hip_runtime.h>
#include <cstdint>
#include <cstddef>

#define S_TOK 8192
#define MDIM  2048
#define NEXP  64
#define CAPTY 256
#define NCHUNK 128   // S_TOK / 64

// ---------------------------------------------------------------------------
// Kernel 1: logits = x @ wg^T, f32, K split in two halves (blockIdx.y).
// Tile: 64 tokens x 64 experts, BK=32, 256 threads, 4x4 register block.
// ---------------------------------------------------------------------------
__global__ __launch_bounds__(256) void gemm_logits(
    const float* __restrict__ x, const float* __restrict__ wg,
    float* __restrict__ outA, float* __restrict__ outB) {
  __shared__ float xs[64][36];
  __shared__ float wsh[64][36];
  const int half = blockIdx.y;
  const int rowBase = blockIdx.x * 64;
  const int kHalf = half * 1024;
  const int t = threadIdx.x;
  const int tx = t & 15;        // expert group: experts tx + 16*b
  const int ty = t >> 4;        // token group: tokens ty*4 + a
  float acc[4][4] = {{0.f}};

  const int rStage = t >> 3;           // 0..31
  const int cStage = (t & 7) << 2;     // 0,4,...,28

  for (int kt = 0; kt < 1024; kt += 32) {
    const int kBase = kHalf + kt;
    // stage x tile (64x32) and full wg tile (64x32)
    for (int rr = rStage; rr < 64; rr += 32) {
      float4 xv = *reinterpret_cast<const float4*>(
          &x[(size_t)(rowBase + rr) * MDIM + kBase + cStage]);
      *reinterpret_cast<float4*>(&xs[rr][cStage]) = xv;
      float4 wv = *reinterpret_cast<const float4*>(
          &wg[(size_t)rr * MDIM + kBase + cStage]);
      *reinterpret_cast<float4*>(&wsh[rr][cStage]) = wv;
    }
    __syncthreads();
#pragma unroll
    for (int k = 0; k < 32; k += 4) {
      float4 xa[4], wb[4];
#pragma unroll
      for (int a = 0; a < 4; ++a)
        xa[a] = *reinterpret_cast<const float4*>(&xs[ty * 4 + a][k]);
#pragma unroll
      for (int b = 0; b < 4; ++b)
        wb[b] = *reinterpret_cast<const float4*>(&wsh[tx + 16 * b][k]);
#pragma unroll
      for (int a = 0; a < 4; ++a)
#pragma unroll
        for (int b = 0; b < 4; ++b) {
          acc[a][b] += xa[a].x * wb[b].x;
          acc[a][b] += xa[a].y * wb[b].y;
          acc[a][b] += xa[a].z * wb[b].z;
          acc[a][b] += xa[a].w * wb[b].w;
        }
    }
    __syncthreads();
  }
  float* out = half ? outB : outA;
#pragma unroll
  for (int a = 0; a < 4; ++a)
#pragma unroll
    for (int b = 0; b < 4; ++b)
      out[(size_t)(rowBase + ty * 4 + a) * NEXP + tx + 16 * b] = acc[a][b];
}

// ---------------------------------------------------------------------------
// Kernel 2: per-token gating. One wave per token, lane = expert.
// Computes e1 (argmax logits), e2 (argmax of gumbel-noised, top1 masked),
// unnormalized top gate values, and accumulates me[e] = sum of softmax gates.
// ---------------------------------------------------------------------------
__global__ __launch_bounds__(1024) void gating(
    const float* __restrict__ la, const float* __restrict__ lb,
    const float* __restrict__ gum,
    int* __restrict__ e1o, int* __restrict__ e2o,
    float* __restrict__ g1o, float* __restrict__ g2o,
    float* __restrict__ me_sum) {
  __shared__ float me_l[NEXP];
  const int t = threadIdx.x;
  if (t < NEXP) me_l[t] = 0.f;
  __syncthreads();

  const int w = t >> 6;
  const int lane = t & 63;
  const int s = blockIdx.x * 16 + w;
  const size_t base = (size_t)s * NEXP + lane;

  const float l = la[base] + lb[base];
  const float gn = gum[base];

  // wave max of logits
  float m = l;
#pragma unroll
  for (int d = 1; d < 64; d <<= 1) m = fmaxf(m, __shfl_xor(m, d, 64));
  const float p = expf(l - m);
  float sum = p;
#pragma unroll
  for (int d = 1; d < 64; d <<= 1) sum += __shfl_xor(sum, d, 64);

  unsigned long long b1 = __ballot(l == m);
  const int e1 = __ffsll(b1) - 1;

  const float y = (lane == e1) ? -INFINITY : (l + gn);
  float m2 = y;
#pragma unroll
  for (int d = 1; d < 64; d <<= 1) m2 = fmaxf(m2, __shfl_xor(m2, d, 64));
  unsigned long long b2 = __ballot(y == m2);
  const int e2 = __ffsll(b2) - 1;

  const float p1 = __shfl(p, e1, 64);
  const float p2 = __shfl(p, e2, 64);

  atomicAdd(&me_l[lane], p / sum);   // softmax gate for this (token, expert)

  if (lane == 0) {
    e1o[s] = e1;
    e2o[s] = e2;
    g1o[s] = p1;
    g2o[s] = p2;
  }
  __syncthreads();
  if (t < NEXP) atomicAdd(&me_sum[t], me_l[t]);
}

// ---------------------------------------------------------------------------
// Kernel 3: within-chunk stable ranks + per-chunk histograms (chunks of 64).
// ---------------------------------------------------------------------------
__global__ __launch_bounds__(64) void rank_chunks(
    const int* __restrict__ e1, const int* __restrict__ e2,
    int* __restrict__ w1, int* __restrict__ w2,
    int* __restrict__ hist1, int* __restrict__ hist2) {
  const int c = blockIdx.x;
  const int lane = threadIdx.x;
  const int s = c * 64 + lane;
  const int a = e1[s];
  const int b = e2[s];
  const unsigned long long lt = (1ull << lane) - 1ull;
  int r1 = 0, r2 = 0;
  for (int e = 0; e < NEXP; ++e) {
    unsigned long long m1 = __ballot(a == e);
    unsigned long long m2 = __ballot(b == e);
    if (a == e) r1 = __popcll(m1 & lt);
    if (b == e) r2 = __popcll(m2 & lt);
    if (lane == e) {
      hist1[c * NEXP + e] = __popcll(m1);
      hist2[c * NEXP + e] = __popcll(m2);
    }
  }
  w1[s] = r1;
  w2[s] = r2;
}

// ---------------------------------------------------------------------------
// Kernel 4: cross-chunk exclusive prefix per expert, l_aux. One wave.
// loc2 offset includes total pre-drop count1[e] (GShard semantics).
// ---------------------------------------------------------------------------
__global__ __launch_bounds__(64) void prefix_aux(
    const int* __restrict__ hist1, const int* __restrict__ hist2,
    const float* __restrict__ me_sum,
    int* __restrict__ off1, int* __restrict__ off2,
    float* __restrict__ out0) {
  const int e = threadIdx.x;
  int run = 0;
  for (int c = 0; c < NCHUNK; ++c) {
    off1[c * NEXP + e] = run;
    run += hist1[c * NEXP + e];
  }
  const int tot1 = run;          // pre-capacity count -> ce * S
  int run2 = tot1;
  for (int c = 0; c < NCHUNK; ++c) {
    off2[c * NEXP + e] = run2;
    run2 += hist2[c * NEXP + e];
  }
  float la = me_sum[e] * (float)tot1;
#pragma unroll
  for (int d = 1; d < 64; d <<= 1) la += __shfl_xor(la, d, 64);
  if (e == 0)
    out0[0] = la * (float)NEXP / ((float)S_TOK * (float)S_TOK);
}

// ---------------------------------------------------------------------------
// Kernel 5: scatter nonzeros into combine_weights / dispatch_mask.
// ---------------------------------------------------------------------------
__global__ __launch_bounds__(256) void scatter(
    const int* __restrict__ e1, const int* __restrict__ e2,
    const int* __restrict__ w1, const int* __restrict__ w2,
    const float* __restrict__ g1r, const float* __restrict__ g2r,
    const int* __restrict__ off1, const int* __restrict__ off2,
    float* __restrict__ out) {
  const int s = blockIdx.x * 256 + threadIdx.x;
  const int c = s >> 6;
  const int a = e1[s];
  const int b = e2[s];
  const int l1 = off1[c * NEXP + a] + w1[s];
  const int l2 = off2[c * NEXP + b] + w2[s];
  const bool k1 = l1 < CAPTY;
  const bool k2 = l2 < CAPTY;
  float p1 = k1 ? g1r[s] : 0.f;
  float p2 = k2 ? g2r[s] : 0.f;
  const float denom = p1 + p2;
  if (denom > 0.f) {
    const float inv = 1.f / denom;
    float* cw = out + 1;
    float* dm = out + 1 + (size_t)S_TOK * NEXP * CAPTY;
    const size_t rowb = (size_t)s * NEXP * CAPTY;
    if (k1) {
      const size_t i1 = rowb + (size_t)a * CAPTY + l1;
      cw[i1] = p1 * inv;
      dm[i1] = 1.f;
    }
    if (k2) {
      const size_t i2 = rowb + (size_t)b * CAPTY + l2;
      cw[i2] = p2 * inv;
      dm[i2] = 1.f;
    }
  }
}

// ---------------------------------------------------------------------------
extern "C" void kernel_launch(void* const* d_in, const int* in_sizes, int n_in,
                              void* d_out, int out_size, void* d_ws,
                              size_t ws_size, hipStream_t stream) {
  const float* x = (const float*)d_in[0];
  const float* wg = (const float*)d_in[1];
  const float* gum = (const float*)d_in[2];
  float* out = (float*)d_out;

  char* w = (char*)d_ws;
  size_t off = 0;
  float* logitsA = (float*)(w + off); off += (size_t)S_TOK * NEXP * 4;
  float* logitsB = (float*)(w + off); off += (size_t)S_TOK * NEXP * 4;
  int*   e1   = (int*)(w + off); off += (size_t)S_TOK * 4;
  int*   e2   = (int*)(w + off); off += (size_t)S_TOK * 4;
  float* g1r  = (float*)(w + off); off += (size_t)S_TOK * 4;
  float* g2r  = (float*)(w + off); off += (size_t)S_TOK * 4;
  int*   w1   = (int*)(w + off); off += (size_t)S_TOK * 4;
  int*   w2   = (int*)(w + off); off += (size_t)S_TOK * 4;
  int*   hist1 = (int*)(w + off); off += (size_t)NCHUNK * NEXP * 4;
  int*   hist2 = (int*)(w + off); off += (size_t)NCHUNK * NEXP * 4;
  int*   off1 = (int*)(w + off); off += (size_t)NCHUNK * NEXP * 4;
  int*   off2 = (int*)(w + off); off += (size_t)NCHUNK * NEXP * 4;
  float* me_sum = (float*)(w + off); off += NEXP * 4;

  // zero the (mostly sparse) output: 1.074 GB — the dominant cost
  hipMemsetAsync(d_out, 0, (size_t)out_size * sizeof(float), stream);
  hipMemsetAsync(me_sum, 0, NEXP * sizeof(float), stream);

  gemm_logits<<<dim3(S_TOK / 64, 2), 256, 0, stream>>>(x, wg, logitsA, logitsB);
  gating<<<S_TOK / 16, 1024, 0, stream>>>(logitsA, logitsB, gum, e1, e2, g1r,
                                          g2r, me_sum);
  rank_chunks<<<NCHUNK, 64, 0, stream>>>(e1, e2, w1, w2, hist1, hist2);
  prefix_aux<<<1, 64, 0, stream>>>(hist1, hist2, me_sum, off1, off2, out);
  scatter<<<S_TOK / 256, 256, 0, stream>>>(e1, e2, w1, w2, g1r, g2r, off1,
                                           off2, out);
}

// Round 9
// 1148.839 us; speedup vs baseline: 1.0119x; 1.0119x over previous
//
#include <hip/hip_runtime.h>
#include <cstdint>
#include <cstddef>

#define S_TOK 8192
#define MDIM  2048
#define NEXP  64
#define CAPTY 256
#define NCHUNK 128   // S_TOK / 64

#define GEMM_BLOCKS 256   // 128 row-tiles x 2 K-halves (bid&1 = half)
#define FILL_BLOCKS 2048  // zero-fill: 2048 blocks x 256 thr x 128 float4 = 1.0737 GB

// ---------------------------------------------------------------------------
// Kernel 1 (fused): blocks [0,256) compute logits = x @ wg^T (f32, K split in
// two halves); blocks [256, 2304) zero-fill the 1.074 GB output. The fill is
// store-BW-bound, the GEMM is VALU-bound: co-resident they overlap, so the
// kernel runs at ~max(fill, gemm) instead of the sum.
// ---------------------------------------------------------------------------
__global__ __launch_bounds__(256) void fill_and_gemm(
    const float* __restrict__ x, const float* __restrict__ wg,
    float* __restrict__ outA, float* __restrict__ outB,
    float* __restrict__ out) {
  const int bid = blockIdx.x;
  const int t = threadIdx.x;

  if (bid >= GEMM_BLOCKS) {
    // ---- zero-fill branch: 67,108,864 float4 total ----
    const int fb = bid - GEMM_BLOCKS;  // 0..2047
    float4 z = {0.f, 0.f, 0.f, 0.f};
    float4* o4 = reinterpret_cast<float4*>(out);
    // grid-stride over float4 space: 2048*256 threads, 128 iters each
    size_t idx = (size_t)fb * 256 + t;
#pragma unroll 8
    for (int i = 0; i < 128; ++i) {
      o4[idx] = z;
      idx += (size_t)FILL_BLOCKS * 256;
    }
    if (fb == 0 && t == 0) out[268435456] = 0.f;  // tail element (out_size-1)
    return;
  }

  // ---- GEMM branch: tile 64 tokens x 64 experts, BK=32, 4x4 per thread ----
  // bid in [0,256): 128 row-tiles (bid>>1), 2 K-halves (bid&1).
  __shared__ float xs[64][36];
  __shared__ float wsh[64][36];
  const int half = bid & 1;                // consecutive blocks share x rows
  const int rowBase = (bid >> 1) * 64;     // <= 8128
  const int kHalf = half * 1024;
  const int tx = t & 15;                   // experts tx + 16*b
  const int ty = t >> 4;                   // tokens ty*4 + a
  float acc[4][4] = {{0.f}};

  const int rStage = t >> 3;               // 0..31
  const int cStage = (t & 7) << 2;         // 0,4,...,28

  for (int kt = 0; kt < 1024; kt += 32) {
    const int kBase = kHalf + kt;
    for (int rr = rStage; rr < 64; rr += 32) {
      float4 xv = *reinterpret_cast<const float4*>(
          &x[(size_t)(rowBase + rr) * MDIM + kBase + cStage]);
      *reinterpret_cast<float4*>(&xs[rr][cStage]) = xv;
      float4 wv = *reinterpret_cast<const float4*>(
          &wg[(size_t)rr * MDIM + kBase + cStage]);
      *reinterpret_cast<float4*>(&wsh[rr][cStage]) = wv;
    }
    __syncthreads();
#pragma unroll
    for (int k = 0; k < 32; k += 4) {
      float4 xa[4], wb[4];
#pragma unroll
      for (int a = 0; a < 4; ++a)
        xa[a] = *reinterpret_cast<const float4*>(&xs[ty * 4 + a][k]);
#pragma unroll
      for (int b = 0; b < 4; ++b)
        wb[b] = *reinterpret_cast<const float4*>(&wsh[tx + 16 * b][k]);
#pragma unroll
      for (int a = 0; a < 4; ++a)
#pragma unroll
        for (int b = 0; b < 4; ++b) {
          acc[a][b] += xa[a].x * wb[b].x;
          acc[a][b] += xa[a].y * wb[b].y;
          acc[a][b] += xa[a].z * wb[b].z;
          acc[a][b] += xa[a].w * wb[b].w;
        }
    }
    __syncthreads();
  }
  float* o = half ? outB : outA;
#pragma unroll
  for (int a = 0; a < 4; ++a)
#pragma unroll
    for (int b = 0; b < 4; ++b)
      o[(size_t)(rowBase + ty * 4 + a) * NEXP + tx + 16 * b] = acc[a][b];
}

// ---------------------------------------------------------------------------
// Kernel 2 (fused gating + within-chunk ranking). One block = one chunk of 64
// tokens. 16 waves; each wave gates 4 tokens (lane = expert). Wave 0 then
// computes stable within-chunk ranks + histograms (lane = token). me partials
// go to global per-chunk (no atomics, no pre-zeroed buffer needed).
// ---------------------------------------------------------------------------
__global__ __launch_bounds__(1024) void gate_rank(
    const float* __restrict__ la, const float* __restrict__ lb,
    const float* __restrict__ gum,
    int* __restrict__ e1o, int* __restrict__ e2o,
    float* __restrict__ g1o, float* __restrict__ g2o,
    float* __restrict__ me_part,  // [NCHUNK][NEXP]
    int* __restrict__ w1, int* __restrict__ w2,
    int* __restrict__ hist1, int* __restrict__ hist2) {
  __shared__ float me_l[NEXP];
  __shared__ int e1_l[64], e2_l[64];
  const int c = blockIdx.x;
  const int t = threadIdx.x;
  const int w = t >> 6;
  const int lane = t & 63;
  if (t < NEXP) me_l[t] = 0.f;
  __syncthreads();

  float me_acc = 0.f;
#pragma unroll
  for (int i = 0; i < 4; ++i) {
    const int s = c * 64 + w * 4 + i;
    const size_t base = (size_t)s * NEXP + lane;
    const float l = la[base] + lb[base];
    const float gn = gum[base];

    float m = l;
#pragma unroll
    for (int d = 1; d < 64; d <<= 1) m = fmaxf(m, __shfl_xor(m, d, 64));
    const float p = expf(l - m);
    float sum = p;
#pragma unroll
    for (int d = 1; d < 64; d <<= 1) sum += __shfl_xor(sum, d, 64);

    unsigned long long b1 = __ballot(l == m);
    const int e1 = __ffsll(b1) - 1;

    const float y = (lane == e1) ? -INFINITY : (l + gn);
    float m2 = y;
#pragma unroll
    for (int d = 1; d < 64; d <<= 1) m2 = fmaxf(m2, __shfl_xor(m2, d, 64));
    unsigned long long b2 = __ballot(y == m2);
    const int e2 = __ffsll(b2) - 1;

    const float p1 = __shfl(p, e1, 64);
    const float p2 = __shfl(p, e2, 64);

    me_acc += p / sum;  // softmax gate for (token s, expert lane)

    if (lane == 0) {
      e1o[s] = e1;
      e2o[s] = e2;
      g1o[s] = p1;
      g2o[s] = p2;
      e1_l[w * 4 + i] = e1;
      e2_l[w * 4 + i] = e2;
    }
  }
  atomicAdd(&me_l[lane], me_acc);
  __syncthreads();

  if (w == 0) {  // ranking: lane = token within chunk
    const int a = e1_l[lane];
    const int b = e2_l[lane];
    const unsigned long long lt = (1ull << lane) - 1ull;
    int r1 = 0, r2 = 0;
    for (int e = 0; e < NEXP; ++e) {
      unsigned long long m1 = __ballot(a == e);
      unsigned long long m2 = __ballot(b == e);
      if (a == e) r1 = __popcll(m1 & lt);
      if (b == e) r2 = __popcll(m2 & lt);
      if (lane == e) {
        hist1[c * NEXP + e] = __popcll(m1);
        hist2[c * NEXP + e] = __popcll(m2);
      }
    }
    w1[c * 64 + lane] = r1;
    w2[c * 64 + lane] = r2;
  }
  if (t < NEXP) me_part[c * NEXP + t] = me_l[t];
}

// ---------------------------------------------------------------------------
// Kernel 3: cross-chunk exclusive prefix per expert, l_aux. One wave.
// ---------------------------------------------------------------------------
__global__ __launch_bounds__(64) void prefix_aux(
    const int* __restrict__ hist1, const int* __restrict__ hist2,
    const float* __restrict__ me_part,
    int* __restrict__ off1, int* __restrict__ off2,
    float* __restrict__ out0) {
  const int e = threadIdx.x;
  int run = 0;
  for (int c = 0; c < NCHUNK; ++c) {
    off1[c * NEXP + e] = run;
    run += hist1[c * NEXP + e];
  }
  const int tot1 = run;  // pre-capacity count -> ce * S
  int run2 = tot1;
  for (int c = 0; c < NCHUNK; ++c) {
    off2[c * NEXP + e] = run2;
    run2 += hist2[c * NEXP + e];
  }
  float ms = 0.f;
  for (int c = 0; c < NCHUNK; ++c) ms += me_part[c * NEXP + e];
  float la = ms * (float)tot1;
#pragma unroll
  for (int d = 1; d < 64; d <<= 1) la += __shfl_xor(la, d, 64);
  if (e == 0)
    out0[0] = la * (float)NEXP / ((float)S_TOK * (float)S_TOK);
}

// ---------------------------------------------------------------------------
// Kernel 4: scatter nonzeros into combine_weights / dispatch_mask.
// ---------------------------------------------------------------------------
__global__ __launch_bounds__(256) void scatter(
    const int* __restrict__ e1, const int* __restrict__ e2,
    const int* __restrict__ w1, const int* __restrict__ w2,
    const float* __restrict__ g1r, const float* __restrict__ g2r,
    const int* __restrict__ off1, const int* __restrict__ off2,
    float* __restrict__ out) {
  const int s = blockIdx.x * 256 + threadIdx.x;
  const int c = s >> 6;
  const int a = e1[s];
  const int b = e2[s];
  const int l1 = off1[c * NEXP + a] + w1[s];
  const int l2 = off2[c * NEXP + b] + w2[s];
  const bool k1 = l1 < CAPTY;
  const bool k2 = l2 < CAPTY;
  float p1 = k1 ? g1r[s] : 0.f;
  float p2 = k2 ? g2r[s] : 0.f;
  const float denom = p1 + p2;
  if (denom > 0.f) {
    const float inv = 1.f / denom;
    float* cw = out + 1;
    float* dm = out + 1 + (size_t)S_TOK * NEXP * CAPTY;
    const size_t rowb = (size_t)s * NEXP * CAPTY;
    if (k1) {
      const size_t i1 = rowb + (size_t)a * CAPTY + l1;
      cw[i1] = p1 * inv;
      dm[i1] = 1.f;
    }
    if (k2) {
      const size_t i2 = rowb + (size_t)b * CAPTY + l2;
      cw[i2] = p2 * inv;
      dm[i2] = 1.f;
    }
  }
}

// ---------------------------------------------------------------------------
extern "C" void kernel_launch(void* const* d_in, const int* in_sizes, int n_in,
                              void* d_out, int out_size, void* d_ws,
                              size_t ws_size, hipStream_t stream) {
  const float* x = (const float*)d_in[0];
  const float* wg = (const float*)d_in[1];
  const float* gum = (const float*)d_in[2];
  float* out = (float*)d_out;

  char* w = (char*)d_ws;
  size_t off = 0;
  float* logitsA = (float*)(w + off); off += (size_t)S_TOK * NEXP * 4;
  float* logitsB = (float*)(w + off); off += (size_t)S_TOK * NEXP * 4;
  int*   e1   = (int*)(w + off); off += (size_t)S_TOK * 4;
  int*   e2   = (int*)(w + off); off += (size_t)S_TOK * 4;
  float* g1r  = (float*)(w + off); off += (size_t)S_TOK * 4;
  float* g2r  = (float*)(w + off); off += (size_t)S_TOK * 4;
  int*   w1   = (int*)(w + off); off += (size_t)S_TOK * 4;
  int*   w2   = (int*)(w + off); off += (size_t)S_TOK * 4;
  int*   hist1 = (int*)(w + off); off += (size_t)NCHUNK * NEXP * 4;
  int*   hist2 = (int*)(w + off); off += (size_t)NCHUNK * NEXP * 4;
  int*   off1 = (int*)(w + off); off += (size_t)NCHUNK * NEXP * 4;
  int*   off2 = (int*)(w + off); off += (size_t)NCHUNK * NEXP * 4;
  float* me_part = (float*)(w + off); off += (size_t)NCHUNK * NEXP * 4;

  fill_and_gemm<<<GEMM_BLOCKS + FILL_BLOCKS, 256, 0, stream>>>(
      x, wg, logitsA, logitsB, out);
  gate_rank<<<NCHUNK, 1024, 0, stream>>>(logitsA, logitsB, gum, e1, e2, g1r,
                                         g2r, me_part, w1, w2, hist1, hist2);
  prefix_aux<<<1, 64, 0, stream>>>(hist1, hist2, me_part, off1, off2, out);
  scatter<<<S_TOK / 256, 256, 0, stream>>>(e1, e2, w1, w2, g1r, g2r, off1,
                                           off2, out);
}